// Round 4
// baseline (192.218 us; speedup 1.0000x reference)
//
#include <hip/hip_runtime.h>

// FeatureRefine, MI355X/gfx950 — round 9.
// R8 post-mortem: refine 52us, VALUBusy 67% -> now VALU-bound. Of ~170
// VALU/p only ~88 are unpack+fma; rest = 20 readfirstlane (scalarization on
// the VALU), 10 cndmask, addr math. Transpose never appears in top-5
// (<51.6us) but non-refine time ~106us is stable -> transpose ~45-50us,
// phase-serialized at 2 blocks/CU.
// R9 changes:
//  1. refine: geo record via 2x s_load_dwordx16 (true SMEM scalar load;
//     offsets premultiplied x512 in geo pass). Kills readfirstlanes.
//  2. refine: v_pk_fma_f32 accumulation (2ch/instr); identity gather
//     dropped — epilogue adds fp32 feat (NCHW coalesced, L3-resident).
//     Fewer ops, less FETCH, better absmax.
//  3. transpose: 128hw x 128ch tiles (34KB LDS, 512thr) -> 4 blocks/CU so
//     load/write phases of neighboring blocks overlap.

#define N_ 4
#define C_ 256
#define H_ 128
#define W_ 128
#define HW_ (H_ * W_)
#define SCALE 0.125f

typedef unsigned int uint32;
typedef uint32 u32x16 __attribute__((ext_vector_type(16)));
typedef float  f32x2  __attribute__((ext_vector_type(2)));

__device__ __forceinline__ uint32 f2bf(float f) {
    uint32 u = __float_as_uint(f);
    u = (u + 0x7FFF + ((u >> 16) & 1)) >> 16;   // RNE
    return u;
}
__device__ __forceinline__ float blo(uint32 u) { return __uint_as_float(u << 16); }
__device__ __forceinline__ float bhi(uint32 u) { return __uint_as_float(u & 0xFFFF0000u); }

// ---------- Pass 0: NCHW fp32 -> NHWC bf16 (packed ch-pairs) + fused geo ----------
// Tile 128 hw x 128 ch (one c-half). 512 thr / 8 waves; LDS [64cp][132]
// = 33.8 KB -> 4 blocks/CU (load/write phases overlap across blocks).
__global__ __launch_bounds__(512, 8) void nchw2nhwc_geo(const float* __restrict__ in,
                                                        const float* __restrict__ bb,
                                                        uint32* __restrict__ outU,
                                                        uint32* __restrict__ geoG)
{
    __shared__ uint32 tile[64 * 132];
    const int t   = threadIdx.x;
    const int l   = t & 63;
    const int g   = t >> 6;               // wave 0..7
    const int lw  = l & 31;
    const int half = l >> 5;
    const int hw0 = blockIdx.x * 128;
    const int ch  = blockIdx.y;           // c-half 0/1
    const int n   = blockIdx.z;

    if (ch == 0 && t < 128) {             // fused geo for this block's pixels
        const int px = n * HW_ + hw0 + t;
        const float* b = bb + (size_t)px * 5;
        const float cx = b[0], cy = b[1], bw = b[2], bh = b[3], th = b[4];
        const float st = sinf(th), ct = cosf(th);
        const float vx = bw * ct * 0.5f, vy = bw * st * 0.5f;
        const float wx = -bh * st * 0.5f, wy = bh * ct * 0.5f;
        const float pxs[5] = {cx, cx + vx + wx, cx - vx + wx, cx - vx - wx, cx + vx - wx};
        const float pys[5] = {cy, cy + vy + wy, cy - vy + wy, cy - vy - wy, cy + vy - wy};
        uint32* gw = geoG + (size_t)px * 32;
#pragma unroll
        for (int p = 0; p < 5; ++p) {
            float x = pxs[p] * SCALE;
            float y = pys[p] * SCALE;
            const bool valid = (y >= -1.0f) && (y <= (float)H_) &&
                               (x >= -1.0f) && (x <= (float)W_);
            y = fmaxf(y, 0.0f);
            x = fmaxf(x, 0.0f);
            int yl = min((int)y, H_ - 1);
            int xl = min((int)x, W_ - 1);
            if (yl >= H_ - 1) y = (float)yl;   // mmcv border snap: ly = 0
            if (xl >= W_ - 1) x = (float)xl;   // lx = 0
            const int yh = min(yl + 1, H_ - 1);
            const float ly = y - (float)yl, lx = x - (float)xl;
            const float hy = 1.0f - ly,     hx = 1.0f - lx;
            const int xa = min(xl, W_ - 2);
            float wA, wB;
            if (xl < W_ - 1) { wA = hx; wB = lx; }
            else             { wA = 0.0f; wB = 1.0f; }
            const float v = valid ? 1.0f : 0.0f;
            gw[p]      = (uint32)((yl * W_ + xa) * 512);   // premul: byte offset
            gw[5 + p]  = (uint32)((yh * W_ + xa) * 512);
            gw[10 + p] = __float_as_uint(v * hy * wA);
            gw[15 + p] = __float_as_uint(v * hy * wB);
            gw[20 + p] = __float_as_uint(v * ly * wA);
            gw[25 + p] = __float_as_uint(v * ly * wB);
        }
        gw[30] = 0u; gw[31] = 0u;
    }

    // channels of this half: ch*128 + 2cp, 2cp+1; cp = g*8 + half*4 + r
    const float* base = in + (size_t)n * C_ * HW_ + (size_t)(ch * 128) * HW_ + hw0 + 4 * lw;
    float4 v0[4], v1[4];
#pragma unroll
    for (int r = 0; r < 4; ++r) {
        const int cp = g * 8 + half * 4 + r;
        v0[r] = *(const float4*)(base + (size_t)(2 * cp) * HW_);
        v1[r] = *(const float4*)(base + (size_t)(2 * cp + 1) * HW_);
    }
#pragma unroll
    for (int r = 0; r < 4; ++r) {
        const int cp = g * 8 + half * 4 + r;
        uint4 u;
        u.x = f2bf(v0[r].x) | (f2bf(v1[r].x) << 16);
        u.y = f2bf(v0[r].y) | (f2bf(v1[r].y) << 16);
        u.z = f2bf(v0[r].z) | (f2bf(v1[r].z) << 16);
        u.w = f2bf(v0[r].w) | (f2bf(v1[r].w) << 16);
        *(uint4*)&tile[cp * 132 + 4 * lw] = u;   // b128, conflict-free (132*4%16==0)
    }
    __syncthreads();
    // this half owns words ch*64..ch*64+63 of each 128-word pixel row
    uint32* dst = outU + ((size_t)n * HW_ + hw0) * 128 + ch * 64;
#pragma unroll
    for (int it = 0; it < 16; ++it) {
        const int f   = it * 512 + t;     // f = row*64 + q
        const int row = f >> 6;           // 0..127
        const int q   = f & 63;
        dst[(size_t)row * 128 + q] = tile[q * 132 + row];  // 8-way LDS, ~1us
    }
}

// ---------- Pass 1: refine v5 — scalar geo via s_load, pk_fma, exact identity ----------
// Block: 256 thr, 32 px x 128 ch (c-half from XCD id). Per point, ONE
// 64-lane x 16B load covers all 4 bilinear corners (4 x 256B segments):
// lane group l>>4: 0=(yl,xa) 1=(yl,xa+1) 2=(yh,xa) 3=(yh,xa+1).
// Geo record (128B, wave-uniform) via 2x s_load_dwordx16 -> SGPRs.
// Accumulate with v_pk_fma_f32 (2 ch / instr). Identity added in the
// epilogue from fp32 feat (exact, coalesced, L3-resident).
__global__ __launch_bounds__(256, 8) void fr_refine(const uint32* __restrict__ nhwcU,
                                                    const uint32* __restrict__ geoG,
                                                    const float* __restrict__ feat,
                                                    float* __restrict__ out)
{
    __shared__ float tile[32 * 128];      // [px][c] fp32, XOR-swizzled, 16 KB
    const int t  = threadIdx.x;
    const int l  = t & 63;
    const int wv = __builtin_amdgcn_readfirstlane(t >> 6);
    const int bx = blockIdx.x;            // [0, 4096)
    // XCD (bx&7) = (batch, c-half): per-XCD gather set = 4MB = one L2.
    const int xcd = bx & 7;
    const int n   = xcd >> 1;
    const int ch  = xcd & 1;
    const int s   = bx >> 3;              // [0, 512) = 128 h x 4 w-tiles
    const int h   = s >> 2;
    const int w0  = (s & 3) * 32;

    // per-lane constant: 16B slot within 256B segment + corner-B (+512B)
    const int laneb = ((l & 15) << 4) + (((l >> 4) & 1) << 9);
    const bool hi = (l >= 32);            // rows yh (corners 2,3)
    const bool b4 = ((l >> 4) & 1) != 0;  // corner-B within row
    const int hwb = h * W_ + w0 + wv * 8;
    const uint32* gb = geoG + ((size_t)n * HW_ + hwb) * 32;
    // fold the c-half byte offset into the plane base
    const char* plane = (const char*)(nhwcU + (size_t)n * HW_ * 128) + (ch << 8);

#pragma unroll 1
    for (int p = 0; p < 8; ++p) {
        const uint32* g = gb + p * 32;    // wave-uniform

        // ---- 128B geo record -> SGPRs (true scalar loads) ----
        u32x16 S0, S1;
        asm volatile("s_load_dwordx16 %0, %2, 0x0\n"
                     "s_load_dwordx16 %1, %2, 0x40\n"
                     "s_waitcnt lgkmcnt(0)\n"
                     : "=&s"(S0), "=&s"(S1)
                     : "s"(g));
        __builtin_amdgcn_sched_barrier(0);
#define GW(i) ((i) < 16 ? S0[(i)] : S1[(i) - 16])

        // ---- per-lane offset/weight selects + issue all 5 gathers ----
        uint4 r[5];
        f32x2 w2[5];
#pragma unroll
        for (int q = 0; q < 5; ++q) {
            const int vof = (int)(hi ? GW(5 + q) : GW(q)) + laneb;  // premul x512
            r[q] = *(const uint4*)(plane + vof);
            const float wq = __uint_as_float(hi ? (b4 ? GW(25 + q) : GW(20 + q))
                                                : (b4 ? GW(15 + q) : GW(10 + q)));
            w2[q].x = wq; w2[q].y = wq;
        }
        __builtin_amdgcn_sched_barrier(0);
#undef GW

        f32x2 acc[4];
#pragma unroll
        for (int k = 0; k < 4; ++k) { acc[k].x = 0.0f; acc[k].y = 0.0f; }
#pragma unroll
        for (int q = 0; q < 5; ++q) {
            f32x2 u0, u1, u2, u3;
            u0.x = blo(r[q].x); u0.y = bhi(r[q].x);
            u1.x = blo(r[q].y); u1.y = bhi(r[q].y);
            u2.x = blo(r[q].z); u2.y = bhi(r[q].z);
            u3.x = blo(r[q].w); u3.y = bhi(r[q].w);
            asm("v_pk_fma_f32 %0, %1, %2, %0" : "+v"(acc[0]) : "v"(u0), "v"(w2[q]));
            asm("v_pk_fma_f32 %0, %1, %2, %0" : "+v"(acc[1]) : "v"(u1), "v"(w2[q]));
            asm("v_pk_fma_f32 %0, %1, %2, %0" : "+v"(acc[2]) : "v"(u2), "v"(w2[q]));
            asm("v_pk_fma_f32 %0, %1, %2, %0" : "+v"(acc[3]) : "v"(u3), "v"(w2[q]));
        }
        // sum the 4 corner groups (butterfly: every lane gets the total)
#pragma unroll
        for (int k = 0; k < 4; ++k) {
            acc[k].x += __shfl_xor(acc[k].x, 16, 64);
            acc[k].y += __shfl_xor(acc[k].y, 16, 64);
            acc[k].x += __shfl_xor(acc[k].x, 32, 64);
            acc[k].y += __shfl_xor(acc[k].y, 32, 64);
        }
        if (l < 16) {                      // lanes 0-15 hold ch 8l..8l+7
            const int px  = wv * 8 + p;
            const int swz = (px & 7) << 2;
            float* base = &tile[px * 128];
            *(float4*)&base[(l * 8) ^ swz]     = make_float4(acc[0].x, acc[0].y, acc[1].x, acc[1].y);
            *(float4*)&base[(l * 8 + 4) ^ swz] = make_float4(acc[2].x, acc[2].y, acc[3].x, acc[3].y);
        }
    }
    __syncthreads();
    // epilogue: out = feat (fp32, exact identity) + acc; swizzled LDS read
    const size_t obase = (size_t)n * C_ * HW_ + (size_t)(ch * 128) * HW_ + h * W_ + w0;
#pragma unroll
    for (int it = 0; it < 16; ++it) {
        const int flat = it * 256 + t;
        const int px = flat & 31;
        const int c  = flat >> 5;          // 0..127
        const size_t idx = obase + (size_t)c * HW_ + px;
        out[idx] = feat[idx] + tile[px * 128 + (c ^ ((px & 7) << 2))];
    }
}

// ---------- Fallback (round-1 kernel) if ws too small ----------
__global__ __launch_bounds__(256) void fr_kernel(
    const float* __restrict__ feat,
    const float* __restrict__ bb,
    float* __restrict__ out)
{
    const int lane = threadIdx.x & 63;
    const int wave = threadIdx.x >> 6;
    const int tile = blockIdx.x;
    const int wt   = tile & 1;
    const int h    = (tile >> 1) & (H_ - 1);
    const int n    = tile >> 8;
    const int w    = wt * 64 + lane;
    const int cb   = blockIdx.y;

    const float* b = bb + (size_t)((n * H_ + h) * W_ + w) * 5;
    const float cx = b[0], cy = b[1], bw = b[2], bh = b[3], th = b[4];
    const float st = sinf(th), ct = cosf(th);
    const float vx = bw * ct * 0.5f, vy = bw * st * 0.5f;
    const float wx = -bh * st * 0.5f, wy = bh * ct * 0.5f;
    const float pxs[5] = {cx, cx + vx + wx, cx - vx + wx, cx - vx - wx, cx + vx - wx};
    const float pys[5] = {cy, cy + vy + wy, cy - vy + wy, cy - vy - wy, cy + vy - wy};

    int   off0[5], off1[5];
    float wgt[20];
#pragma unroll
    for (int p = 0; p < 5; ++p) {
        float x = pxs[p] * SCALE;
        float y = pys[p] * SCALE;
        const bool valid = (y >= -1.0f) && (y <= (float)H_) &&
                           (x >= -1.0f) && (x <= (float)W_);
        y = fmaxf(y, 0.0f);
        x = fmaxf(x, 0.0f);
        int yl = min((int)y, H_ - 1);
        int xl = min((int)x, W_ - 1);
        if (yl >= H_ - 1) y = (float)yl;
        if (xl >= W_ - 1) x = (float)xl;
        const int yh = min(yl + 1, H_ - 1);
        const float ly = y - (float)yl, lx = x - (float)xl;
        const float hy = 1.0f - ly,     hx = 1.0f - lx;
        const int xa = min(xl, W_ - 2);
        float wA, wB;
        if (xl < W_ - 1) { wA = hx; wB = lx; }
        else             { wA = 0.0f; wB = 1.0f; }
        const float v = valid ? 1.0f : 0.0f;
        off0[p] = yl * W_ + xa;
        off1[p] = yh * W_ + xa;
        wgt[p * 4 + 0] = v * hy * wA;
        wgt[p * 4 + 1] = v * hy * wB;
        wgt[p * 4 + 2] = v * ly * wA;
        wgt[p * 4 + 3] = v * ly * wB;
    }

    const int hw = h * W_ + w;
    const size_t planeBase = ((size_t)n * C_ + cb * 64 + wave * 16) * HW_;
    const float* fp = feat + planeBase;
    float*       op = out  + planeBase;
    for (int it = 0; it < 16; ++it) {
        float acc = fp[hw];
#pragma unroll
        for (int p = 0; p < 5; ++p) {
            acc += wgt[p * 4 + 0] * fp[off0[p]]
                 + wgt[p * 4 + 1] * fp[off0[p] + 1]
                 + wgt[p * 4 + 2] * fp[off1[p]]
                 + wgt[p * 4 + 3] * fp[off1[p] + 1];
        }
        op[hw] = acc;
        fp += HW_;
        op += HW_;
    }
}

extern "C" void kernel_launch(void* const* d_in, const int* in_sizes, int n_in,
                              void* d_out, int out_size, void* d_ws, size_t ws_size,
                              hipStream_t stream) {
    const float* feat = (const float*)d_in[0];   // [N,C,H,W] fp32
    const float* bbox = (const float*)d_in[1];   // [N,H,W,5] fp32
    float* out = (float*)d_out;

    const size_t nhwcBytes = (size_t)N_ * HW_ * C_ * 2;        // 32 MB bf16
    const size_t geoBytes  = (size_t)N_ * HW_ * 32 * 4;        // 8 MB
    if (ws_size >= nhwcBytes + geoBytes) {
        uint32* nhwcU = (uint32*)d_ws;
        uint32* geoG  = (uint32*)((char*)d_ws + nhwcBytes);
        nchw2nhwc_geo<<<dim3(HW_ / 128, 2, N_), dim3(512), 0, stream>>>(feat, bbox, nhwcU, geoG);
        fr_refine<<<dim3(N_ * H_ * (W_ / 32) * 2), dim3(256), 0, stream>>>(nhwcU, geoG, feat, out);
    } else {
        dim3 grid(N_ * H_ * (W_ / 64), C_ / 64, 1);
        fr_kernel<<<grid, dim3(256), 0, stream>>>(feat, bbox, out);
    }
}

// Round 5
// 167.361 us; speedup vs baseline: 1.1485x; 1.1485x over previous
//
#include <hip/hip_runtime.h>

// FeatureRefine, MI355X/gfx950 — round 10.
// R9 post-mortem: inline-asm s_load + divergent SGPR selects forced mass
// v_mov s->v copies (VALU can read 1 SGPR/instr) -> VALUBusy 101%, 81us.
// Fp32-feat epilogue added 54MB FETCH. Full revert to R8 (52us proven) plus:
//  1. geo record re-keyed BY CORNER: per point 4 x (byte_ofs premul x512,
//     weight). Refine: one 8B broadcast load per point at gq+q*32+(l>>4)*8 —
//     NO selects, NO readfirstlane, NO shifts. Record 160B/px (10.5MB).
//  2. f32x2 ext-vector accumulate -> v_pk_fma_f32 (3 VALU/pair vs 4).
//  3. transpose + identity-gather + epilogue: exact R8 versions.

#define N_ 4
#define C_ 256
#define H_ 128
#define W_ 128
#define HW_ (H_ * W_)
#define SCALE 0.125f

typedef unsigned int uint32;
typedef float f32x2 __attribute__((ext_vector_type(2)));

__device__ __forceinline__ uint32 f2bf(float f) {
    uint32 u = __float_as_uint(f);
    u = (u + 0x7FFF + ((u >> 16) & 1)) >> 16;   // RNE
    return u;
}
__device__ __forceinline__ float blo(uint32 u) { return __uint_as_float(u << 16); }
__device__ __forceinline__ float bhi(uint32 u) { return __uint_as_float(u & 0xFFFF0000u); }

// ---------- Pass 0: NCHW fp32 -> NHWC bf16 (packed ch-pairs) + fused geo ----------
// Tile 256 hw x 128 ch (one c-half). 1024 thr / 16 waves; 4 cpairs per wave.
// LDS [64 cpair][256 hw + pad] = 66.5 KB -> 2 blocks/CU. (R8-proven version.)
__global__ __launch_bounds__(1024, 8) void nchw2nhwc_geo(const float* __restrict__ in,
                                                         const float* __restrict__ bb,
                                                         uint32* __restrict__ outU,
                                                         uint32* __restrict__ geoG)
{
    __shared__ uint32 tile[64 * 260];
    const int t   = threadIdx.x;
    const int l   = t & 63;
    const int g   = t >> 6;               // wave 0..15
    const int hw0 = blockIdx.x * 256;
    const int ch  = blockIdx.y;           // c-half 0/1
    const int n   = blockIdx.z;

    if (ch == 0 && t < 256) {             // fused geo for this block's pixels
        const int px = n * HW_ + hw0 + t;
        const float* b = bb + (size_t)px * 5;
        const float cx = b[0], cy = b[1], bw = b[2], bh = b[3], th = b[4];
        const float st = sinf(th), ct = cosf(th);
        const float vx = bw * ct * 0.5f, vy = bw * st * 0.5f;
        const float wx = -bh * st * 0.5f, wy = bh * ct * 0.5f;
        const float pxs[5] = {cx, cx + vx + wx, cx - vx + wx, cx - vx - wx, cx + vx - wx};
        const float pys[5] = {cy, cy + vy + wy, cy - vy + wy, cy - vy - wy, cy + vy - wy};
        uint32* gw = geoG + (size_t)px * 40;   // 160B record: 5 pts x 4 corners x 8B
#pragma unroll
        for (int p = 0; p < 5; ++p) {
            float x = pxs[p] * SCALE;
            float y = pys[p] * SCALE;
            const bool valid = (y >= -1.0f) && (y <= (float)H_) &&
                               (x >= -1.0f) && (x <= (float)W_);
            y = fmaxf(y, 0.0f);
            x = fmaxf(x, 0.0f);
            int yl = min((int)y, H_ - 1);
            int xl = min((int)x, W_ - 1);
            if (yl >= H_ - 1) y = (float)yl;   // mmcv border snap: ly = 0
            if (xl >= W_ - 1) x = (float)xl;   // lx = 0
            const int yh = min(yl + 1, H_ - 1);
            const float ly = y - (float)yl, lx = x - (float)xl;
            const float hy = 1.0f - ly,     hx = 1.0f - lx;
            const int xa = min(xl, W_ - 2);
            float wA, wB;
            if (xl < W_ - 1) { wA = hx; wB = lx; }
            else             { wA = 0.0f; wB = 1.0f; }
            const float v = valid ? 1.0f : 0.0f;
            const int pix0 = yl * W_ + xa;
            const int pix1 = yh * W_ + xa;
            // corner k = (row<<1)|xB: 0=(yl,xa) 1=(yl,xa+1) 2=(yh,xa) 3=(yh,xa+1)
            *(uint4*)&gw[p * 8]     = make_uint4((uint32)(pix0 * 512),
                                                 __float_as_uint(v * hy * wA),
                                                 (uint32)((pix0 + 1) * 512),
                                                 __float_as_uint(v * hy * wB));
            *(uint4*)&gw[p * 8 + 4] = make_uint4((uint32)(pix1 * 512),
                                                 __float_as_uint(v * ly * wA),
                                                 (uint32)((pix1 + 1) * 512),
                                                 __float_as_uint(v * ly * wB));
        }
    }

    // channels of this half: ch*128 + 2cp, 2cp+1 for cp = 0..63
    const float* base = in + (size_t)n * C_ * HW_ + (size_t)(ch * 128) * HW_ + hw0 + 4 * l;
    float4 v0[4], v1[4];
#pragma unroll
    for (int r = 0; r < 4; ++r) {
        const int cp = g * 4 + r;
        v0[r] = *(const float4*)(base + (size_t)(2 * cp) * HW_);
        v1[r] = *(const float4*)(base + (size_t)(2 * cp + 1) * HW_);
    }
#pragma unroll
    for (int r = 0; r < 4; ++r) {
        const int cp = g * 4 + r;
        uint4 u;
        u.x = f2bf(v0[r].x) | (f2bf(v1[r].x) << 16);
        u.y = f2bf(v0[r].y) | (f2bf(v1[r].y) << 16);
        u.z = f2bf(v0[r].z) | (f2bf(v1[r].z) << 16);
        u.w = f2bf(v0[r].w) | (f2bf(v1[r].w) << 16);
        *(uint4*)&tile[cp * 260 + 4 * l] = u;   // b128, conflict-free
    }
    __syncthreads();
    // this half owns words ch*64..ch*64+63 of each 128-word pixel row
    uint32* dst = outU + ((size_t)n * HW_ + hw0) * 128 + ch * 64;
#pragma unroll
    for (int it = 0; it < 16; ++it) {
        const int f   = it * 1024 + t;    // f = row*64 + q
        const int row = f >> 6;           // 0..255
        const int q   = f & 63;
        dst[(size_t)row * 128 + q] = tile[q * 260 + row];
    }
}

// ---------- Pass 1: refine v6 — corner-keyed geo, pk_fma ----------
// Block: 256 thr, 32 px x 128 ch (c-half from XCD id). Per point, ONE
// 64-lane x 16B load covers all 4 bilinear corners (4 x 256B segments);
// lane group k = l>>4 is the corner id. Geo: one 8B broadcast load per
// point per lane (its corner's {ofs, w}) — zero selects. Accumulate in
// f32x2 (v_pk_fma_f32). Corner reduce: shfl_xor 16 then 32.
__global__ __launch_bounds__(256, 8) void fr_refine(const uint32* __restrict__ nhwcU,
                                                    const uint32* __restrict__ geoG,
                                                    float* __restrict__ out)
{
    __shared__ float tile[32 * 128];      // [px][c] fp32, XOR-swizzled, 16 KB
    const int t  = threadIdx.x;
    const int l  = t & 63;
    const int wv = __builtin_amdgcn_readfirstlane(t >> 6);
    const int bx = blockIdx.x;            // [0, 4096)
    // XCD (bx&7) = (batch, c-half): per-XCD gather set = 4MB = one L2.
    const int xcd = bx & 7;
    const int n   = xcd >> 1;
    const int ch  = xcd & 1;
    const int s   = bx >> 3;              // [0, 512) = 128 h x 4 w-tiles
    const int h   = s >> 2;
    const int w0  = (s & 3) * 32;

    const int k8   = (l >> 4) << 3;       // corner id * 8 bytes
    const int slot = (l & 15) << 4;       // 16B slot within 256B segment
    const int hwb  = h * W_ + w0 + wv * 8;
    const char* gbase = (const char*)geoG + (size_t)(n * HW_ + hwb) * 160;
    // c-half byte offset folded into the plane base
    const char* plane = (const char*)(nhwcU + (size_t)n * HW_ * 128) + (ch << 8);

#pragma unroll 1
    for (int p = 0; p < 8; ++p) {
        const char* gq = gbase + p * 160;

        // per-corner geo: 5 x 8B loads (broadcast within each 16-lane group)
        uint2 ow[5];
#pragma unroll
        for (int q = 0; q < 5; ++q)
            ow[q] = *(const uint2*)(gq + q * 32 + k8);

        // identity (corner group 0 only) + 5 four-corner gathers
        uint4 rid = make_uint4(0u, 0u, 0u, 0u);
        if (l < 16)
            rid = *(const uint4*)(plane + (size_t)(hwb + p) * 512 + slot);
        uint4 r[5];
#pragma unroll
        for (int q = 0; q < 5; ++q)
            r[q] = *(const uint4*)(plane + ow[q].x + slot);
        __builtin_amdgcn_sched_barrier(0);

        f32x2 acc0, acc1, acc2, acc3;
        acc0.x = blo(rid.x); acc0.y = bhi(rid.x);
        acc1.x = blo(rid.y); acc1.y = bhi(rid.y);
        acc2.x = blo(rid.z); acc2.y = bhi(rid.z);
        acc3.x = blo(rid.w); acc3.y = bhi(rid.w);
#pragma unroll
        for (int q = 0; q < 5; ++q) {
            const float w = __uint_as_float(ow[q].y);
            f32x2 w2; w2.x = w; w2.y = w;
            f32x2 u;
            u.x = blo(r[q].x); u.y = bhi(r[q].x); acc0 += u * w2;
            u.x = blo(r[q].y); u.y = bhi(r[q].y); acc1 += u * w2;
            u.x = blo(r[q].z); u.y = bhi(r[q].z); acc2 += u * w2;
            u.x = blo(r[q].w); u.y = bhi(r[q].w); acc3 += u * w2;
        }
        float a[8] = {acc0.x, acc0.y, acc1.x, acc1.y,
                      acc2.x, acc2.y, acc3.x, acc3.y};
        // sum the 4 corner groups (butterfly: every lane gets the total)
#pragma unroll
        for (int k = 0; k < 8; ++k) {
            a[k] += __shfl_xor(a[k], 16, 64);
            a[k] += __shfl_xor(a[k], 32, 64);
        }
        if (l < 16) {                      // lanes 0-15 hold ch 8l..8l+7
            const int px  = wv * 8 + p;
            const int swz = (px & 7) << 2;
            float* base = &tile[px * 128];
            *(float4*)&base[(l * 8) ^ swz]     = make_float4(a[0], a[1], a[2], a[3]);
            *(float4*)&base[(l * 8 + 4) ^ swz] = make_float4(a[4], a[5], a[6], a[7]);
        }
    }
    __syncthreads();
    // epilogue: [32px][128c] -> NCHW; swizzled read is 4-way (~free)
    const size_t obase = (size_t)n * C_ * HW_ + (size_t)(ch * 128) * HW_ + h * W_ + w0;
#pragma unroll
    for (int it = 0; it < 16; ++it) {
        const int flat = it * 256 + t;
        const int px = flat & 31;
        const int c  = flat >> 5;          // 0..127
        out[obase + (size_t)c * HW_ + px] = tile[px * 128 + (c ^ ((px & 7) << 2))];
    }
}

// ---------- Fallback (round-1 kernel) if ws too small ----------
__global__ __launch_bounds__(256) void fr_kernel(
    const float* __restrict__ feat,
    const float* __restrict__ bb,
    float* __restrict__ out)
{
    const int lane = threadIdx.x & 63;
    const int wave = threadIdx.x >> 6;
    const int tile = blockIdx.x;
    const int wt   = tile & 1;
    const int h    = (tile >> 1) & (H_ - 1);
    const int n    = tile >> 8;
    const int w    = wt * 64 + lane;
    const int cb   = blockIdx.y;

    const float* b = bb + (size_t)((n * H_ + h) * W_ + w) * 5;
    const float cx = b[0], cy = b[1], bw = b[2], bh = b[3], th = b[4];
    const float st = sinf(th), ct = cosf(th);
    const float vx = bw * ct * 0.5f, vy = bw * st * 0.5f;
    const float wx = -bh * st * 0.5f, wy = bh * ct * 0.5f;
    const float pxs[5] = {cx, cx + vx + wx, cx - vx + wx, cx - vx - wx, cx + vx - wx};
    const float pys[5] = {cy, cy + vy + wy, cy - vy + wy, cy - vy - wy, cy + vy - wy};

    int   off0[5], off1[5];
    float wgt[20];
#pragma unroll
    for (int p = 0; p < 5; ++p) {
        float x = pxs[p] * SCALE;
        float y = pys[p] * SCALE;
        const bool valid = (y >= -1.0f) && (y <= (float)H_) &&
                           (x >= -1.0f) && (x <= (float)W_);
        y = fmaxf(y, 0.0f);
        x = fmaxf(x, 0.0f);
        int yl = min((int)y, H_ - 1);
        int xl = min((int)x, W_ - 1);
        if (yl >= H_ - 1) y = (float)yl;
        if (xl >= W_ - 1) x = (float)xl;
        const int yh = min(yl + 1, H_ - 1);
        const float ly = y - (float)yl, lx = x - (float)xl;
        const float hy = 1.0f - ly,     hx = 1.0f - lx;
        const int xa = min(xl, W_ - 2);
        float wA, wB;
        if (xl < W_ - 1) { wA = hx; wB = lx; }
        else             { wA = 0.0f; wB = 1.0f; }
        const float v = valid ? 1.0f : 0.0f;
        off0[p] = yl * W_ + xa;
        off1[p] = yh * W_ + xa;
        wgt[p * 4 + 0] = v * hy * wA;
        wgt[p * 4 + 1] = v * hy * wB;
        wgt[p * 4 + 2] = v * ly * wA;
        wgt[p * 4 + 3] = v * ly * wB;
    }

    const int hw = h * W_ + w;
    const size_t planeBase = ((size_t)n * C_ + cb * 64 + wave * 16) * HW_;
    const float* fp = feat + planeBase;
    float*       op = out  + planeBase;
    for (int it = 0; it < 16; ++it) {
        float acc = fp[hw];
#pragma unroll
        for (int p = 0; p < 5; ++p) {
            acc += wgt[p * 4 + 0] * fp[off0[p]]
                 + wgt[p * 4 + 1] * fp[off0[p] + 1]
                 + wgt[p * 4 + 2] * fp[off1[p]]
                 + wgt[p * 4 + 3] * fp[off1[p] + 1];
        }
        op[hw] = acc;
        fp += HW_;
        op += HW_;
    }
}

extern "C" void kernel_launch(void* const* d_in, const int* in_sizes, int n_in,
                              void* d_out, int out_size, void* d_ws, size_t ws_size,
                              hipStream_t stream) {
    const float* feat = (const float*)d_in[0];   // [N,C,H,W] fp32
    const float* bbox = (const float*)d_in[1];   // [N,H,W,5] fp32
    float* out = (float*)d_out;

    const size_t nhwcBytes = (size_t)N_ * HW_ * C_ * 2;        // 32 MB bf16
    const size_t geoBytes  = (size_t)N_ * HW_ * 160;           // 10.5 MB
    if (ws_size >= nhwcBytes + geoBytes) {
        uint32* nhwcU = (uint32*)d_ws;
        uint32* geoG  = (uint32*)((char*)d_ws + nhwcBytes);
        nchw2nhwc_geo<<<dim3(HW_ / 256, 2, N_), dim3(1024), 0, stream>>>(feat, bbox, nhwcU, geoG);
        fr_refine<<<dim3(N_ * H_ * (W_ / 32) * 2), dim3(256), 0, stream>>>(nhwcU, geoG, out);
    } else {
        dim3 grid(N_ * H_ * (W_ / 64), C_ / 64, 1);
        fr_kernel<<<grid, dim3(256), 0, stream>>>(feat, bbox, out);
    }
}

// Round 7
// 166.477 us; speedup vs baseline: 1.1546x; 1.0053x over previous
//
#include <hip/hip_runtime.h>

// FeatureRefine, MI355X/gfx950 — round 12 (R11 resubmit; container infra
// failure last round, no measurement).
// R10 post-mortem: corner-keyed geo cut VALU as predicted (67->38%) but dur
// 52->61us: per-lane geo load -> gather = serial vmem->vmem chain each
// iteration, and VGPR=28 killed in-flight payload. Latency-bound; all
// resource floors (VALU 23us, HBM 24us, L2 20us) sit at ~25us.
// Changes vs R10:
//  1. refine: 2-deep software pipeline. Iteration p issues geo(p+2) and
//     gathers(p+1), then computes p. launch_bounds(256,4) -> ~100 VGPR for
//     two in-flight stages; sched_barrier(0) pins issue order (R6 lesson).
//  2. transpose: epilogue regrouped to uint4 stores (16B/lane, 4x fewer
//     store instrs, same 256B segments) — tests store-issue-bound theory.

#define N_ 4
#define C_ 256
#define H_ 128
#define W_ 128
#define HW_ (H_ * W_)
#define SCALE 0.125f

typedef unsigned int uint32;
typedef float f32x2 __attribute__((ext_vector_type(2)));

__device__ __forceinline__ uint32 f2bf(float f) {
    uint32 u = __float_as_uint(f);
    u = (u + 0x7FFF + ((u >> 16) & 1)) >> 16;   // RNE
    return u;
}
__device__ __forceinline__ float blo(uint32 u) { return __uint_as_float(u << 16); }
__device__ __forceinline__ float bhi(uint32 u) { return __uint_as_float(u & 0xFFFF0000u); }

// ---------- Pass 0: NCHW fp32 -> NHWC bf16 (packed ch-pairs) + fused geo ----------
// Tile 256 hw x 128 ch (one c-half). 1024 thr / 16 waves; 4 cpairs per wave.
// LDS [64 cpair][256 hw + pad] = 66.5 KB -> 2 blocks/CU.
__global__ __launch_bounds__(1024, 8) void nchw2nhwc_geo(const float* __restrict__ in,
                                                         const float* __restrict__ bb,
                                                         uint32* __restrict__ outU,
                                                         uint32* __restrict__ geoG)
{
    __shared__ uint32 tile[64 * 260];
    const int t   = threadIdx.x;
    const int l   = t & 63;
    const int g   = t >> 6;               // wave 0..15
    const int hw0 = blockIdx.x * 256;
    const int ch  = blockIdx.y;           // c-half 0/1
    const int n   = blockIdx.z;

    if (ch == 0 && t < 256) {             // fused geo for this block's pixels
        const int px = n * HW_ + hw0 + t;
        const float* b = bb + (size_t)px * 5;
        const float cx = b[0], cy = b[1], bw = b[2], bh = b[3], th = b[4];
        const float st = sinf(th), ct = cosf(th);
        const float vx = bw * ct * 0.5f, vy = bw * st * 0.5f;
        const float wx = -bh * st * 0.5f, wy = bh * ct * 0.5f;
        const float pxs[5] = {cx, cx + vx + wx, cx - vx + wx, cx - vx - wx, cx + vx - wx};
        const float pys[5] = {cy, cy + vy + wy, cy - vy + wy, cy - vy - wy, cy + vy - wy};
        uint32* gw = geoG + (size_t)px * 40;   // 160B: 5 pts x 4 corners x 8B
#pragma unroll
        for (int p = 0; p < 5; ++p) {
            float x = pxs[p] * SCALE;
            float y = pys[p] * SCALE;
            const bool valid = (y >= -1.0f) && (y <= (float)H_) &&
                               (x >= -1.0f) && (x <= (float)W_);
            y = fmaxf(y, 0.0f);
            x = fmaxf(x, 0.0f);
            int yl = min((int)y, H_ - 1);
            int xl = min((int)x, W_ - 1);
            if (yl >= H_ - 1) y = (float)yl;   // mmcv border snap: ly = 0
            if (xl >= W_ - 1) x = (float)xl;   // lx = 0
            const int yh = min(yl + 1, H_ - 1);
            const float ly = y - (float)yl, lx = x - (float)xl;
            const float hy = 1.0f - ly,     hx = 1.0f - lx;
            const int xa = min(xl, W_ - 2);
            float wA, wB;
            if (xl < W_ - 1) { wA = hx; wB = lx; }
            else             { wA = 0.0f; wB = 1.0f; }
            const float v = valid ? 1.0f : 0.0f;
            const int pix0 = yl * W_ + xa;
            const int pix1 = yh * W_ + xa;
            // corner k: 0=(yl,xa) 1=(yl,xa+1) 2=(yh,xa) 3=(yh,xa+1)
            *(uint4*)&gw[p * 8]     = make_uint4((uint32)(pix0 * 512),
                                                 __float_as_uint(v * hy * wA),
                                                 (uint32)((pix0 + 1) * 512),
                                                 __float_as_uint(v * hy * wB));
            *(uint4*)&gw[p * 8 + 4] = make_uint4((uint32)(pix1 * 512),
                                                 __float_as_uint(v * ly * wA),
                                                 (uint32)((pix1 + 1) * 512),
                                                 __float_as_uint(v * ly * wB));
        }
    }

    // channels of this half: ch*128 + 2cp, 2cp+1 for cp = 0..63
    const float* base = in + (size_t)n * C_ * HW_ + (size_t)(ch * 128) * HW_ + hw0 + 4 * l;
    float4 v0[4], v1[4];
#pragma unroll
    for (int r = 0; r < 4; ++r) {
        const int cp = g * 4 + r;
        v0[r] = *(const float4*)(base + (size_t)(2 * cp) * HW_);
        v1[r] = *(const float4*)(base + (size_t)(2 * cp + 1) * HW_);
    }
#pragma unroll
    for (int r = 0; r < 4; ++r) {
        const int cp = g * 4 + r;
        uint4 u;
        u.x = f2bf(v0[r].x) | (f2bf(v1[r].x) << 16);
        u.y = f2bf(v0[r].y) | (f2bf(v1[r].y) << 16);
        u.z = f2bf(v0[r].z) | (f2bf(v1[r].z) << 16);
        u.w = f2bf(v0[r].w) | (f2bf(v1[r].w) << 16);
        *(uint4*)&tile[cp * 260 + 4 * l] = u;   // b128, conflict-free
    }
    __syncthreads();
    // epilogue v2: 16B/lane uint4 stores. Per iter: 64 px, 16 thr/px.
    // Store addr: px*128 + cp0 -> 16 lanes = 256B contiguous, 4 px/instr.
    uint32* dst = outU + ((size_t)n * HW_ + hw0) * 128 + ch * 64;
#pragma unroll
    for (int it = 0; it < 4; ++it) {
        const int px  = it * 64 + (t >> 4);   // 0..255
        const int cp0 = (t & 15) * 4;
        uint4 v;
        v.x = tile[(cp0 + 0) * 260 + px];
        v.y = tile[(cp0 + 1) * 260 + px];
        v.z = tile[(cp0 + 2) * 260 + px];
        v.w = tile[(cp0 + 3) * 260 + px];
        *(uint4*)&dst[(size_t)px * 128 + cp0] = v;
    }
}

// ---------- Pass 1: refine v7 — corner-keyed geo, 2-deep pipeline ----------
// Block: 256 thr, 32 px x 128 ch (c-half from XCD id). Per point, ONE
// 64-lane x 16B load covers all 4 bilinear corners; lane group l>>4 is the
// corner id. Pipeline: iter p issues geo(p+2) + gathers(p+1), computes p.
__global__ __launch_bounds__(256, 4) void fr_refine(const uint32* __restrict__ nhwcU,
                                                    const uint32* __restrict__ geoG,
                                                    float* __restrict__ out)
{
    __shared__ float tile[32 * 128];      // [px][c] fp32, XOR-swizzled, 16 KB
    const int t  = threadIdx.x;
    const int l  = t & 63;
    const int wv = __builtin_amdgcn_readfirstlane(t >> 6);
    const int bx = blockIdx.x;            // [0, 4096)
    // XCD (bx&7) = (batch, c-half): per-XCD gather set = 4MB = one L2.
    const int xcd = bx & 7;
    const int n   = xcd >> 1;
    const int ch  = xcd & 1;
    const int s   = bx >> 3;              // [0, 512) = 128 h x 4 w-tiles
    const int h   = s >> 2;
    const int w0  = (s & 3) * 32;

    const int k8   = (l >> 4) << 3;       // corner id * 8 bytes
    const int slot = (l & 15) << 4;       // 16B slot within 256B segment
    const int hwb  = h * W_ + w0 + wv * 8;
    const char* gbase = (const char*)geoG + (size_t)(n * HW_ + hwb) * 160;
    const char* plane = (const char*)(nhwcU + (size_t)n * HW_ * 128) + (ch << 8);
    const bool idlane = (l < 16);

    uint2 owA[5], owB[5], owC[5];
    uint4 rA[5], rB[5];
    uint4 ridA, ridB;

    // ---- prologue: geo(0), geo(1), gather(0) ----
#pragma unroll
    for (int q = 0; q < 5; ++q) owA[q] = *(const uint2*)(gbase + q * 32 + k8);
#pragma unroll
    for (int q = 0; q < 5; ++q) owB[q] = *(const uint2*)(gbase + 160 + q * 32 + k8);
    ridA = make_uint4(0u, 0u, 0u, 0u);
    if (idlane) ridA = *(const uint4*)(plane + (size_t)hwb * 512 + slot);
#pragma unroll
    for (int q = 0; q < 5; ++q) rA[q] = *(const uint4*)(plane + owA[q].x + slot);
    __builtin_amdgcn_sched_barrier(0);

#pragma unroll
    for (int p = 0; p < 8; ++p) {
        // stage 1: issue geo(p+2)
        if (p + 2 < 8) {
#pragma unroll
            for (int q = 0; q < 5; ++q)
                owC[q] = *(const uint2*)(gbase + (p + 2) * 160 + q * 32 + k8);
        }
        // stage 2: issue gathers(p+1) from owB (loaded one iter ago)
        if (p + 1 < 8) {
            ridB = make_uint4(0u, 0u, 0u, 0u);
            if (idlane) ridB = *(const uint4*)(plane + (size_t)(hwb + p + 1) * 512 + slot);
#pragma unroll
            for (int q = 0; q < 5; ++q)
                rB[q] = *(const uint4*)(plane + owB[q].x + slot);
        }
        __builtin_amdgcn_sched_barrier(0);

        // stage 3: compute p from rA / owA weights
        f32x2 acc0, acc1, acc2, acc3;
        acc0.x = blo(ridA.x); acc0.y = bhi(ridA.x);
        acc1.x = blo(ridA.y); acc1.y = bhi(ridA.y);
        acc2.x = blo(ridA.z); acc2.y = bhi(ridA.z);
        acc3.x = blo(ridA.w); acc3.y = bhi(ridA.w);
#pragma unroll
        for (int q = 0; q < 5; ++q) {
            const float w = __uint_as_float(owA[q].y);
            f32x2 w2; w2.x = w; w2.y = w;
            f32x2 u;
            u.x = blo(rA[q].x); u.y = bhi(rA[q].x); acc0 += u * w2;
            u.x = blo(rA[q].y); u.y = bhi(rA[q].y); acc1 += u * w2;
            u.x = blo(rA[q].z); u.y = bhi(rA[q].z); acc2 += u * w2;
            u.x = blo(rA[q].w); u.y = bhi(rA[q].w); acc3 += u * w2;
        }
        float a[8] = {acc0.x, acc0.y, acc1.x, acc1.y,
                      acc2.x, acc2.y, acc3.x, acc3.y};
#pragma unroll
        for (int k = 0; k < 8; ++k) {
            a[k] += __shfl_xor(a[k], 16, 64);
            a[k] += __shfl_xor(a[k], 32, 64);
        }
        if (idlane) {                      // lanes 0-15 hold ch 8l..8l+7
            const int px  = wv * 8 + p;
            const int swz = (px & 7) << 2;
            float* base = &tile[px * 128];
            *(float4*)&base[(l * 8) ^ swz]     = make_float4(a[0], a[1], a[2], a[3]);
            *(float4*)&base[(l * 8 + 4) ^ swz] = make_float4(a[4], a[5], a[6], a[7]);
        }

        // rotate pipeline registers (renamed by full unroll)
#pragma unroll
        for (int q = 0; q < 5; ++q) { owA[q] = owB[q]; owB[q] = owC[q]; rA[q] = rB[q]; }
        ridA = ridB;
    }
    __syncthreads();
    // epilogue: [32px][128c] -> NCHW; swizzled read is 4-way (~free)
    const size_t obase = (size_t)n * C_ * HW_ + (size_t)(ch * 128) * HW_ + h * W_ + w0;
#pragma unroll
    for (int it = 0; it < 16; ++it) {
        const int flat = it * 256 + t;
        const int px = flat & 31;
        const int c  = flat >> 5;          // 0..127
        out[obase + (size_t)c * HW_ + px] = tile[px * 128 + (c ^ ((px & 7) << 2))];
    }
}

// ---------- Fallback (round-1 kernel) if ws too small ----------
__global__ __launch_bounds__(256) void fr_kernel(
    const float* __restrict__ feat,
    const float* __restrict__ bb,
    float* __restrict__ out)
{
    const int lane = threadIdx.x & 63;
    const int wave = threadIdx.x >> 6;
    const int tile = blockIdx.x;
    const int wt   = tile & 1;
    const int h    = (tile >> 1) & (H_ - 1);
    const int n    = tile >> 8;
    const int w    = wt * 64 + lane;
    const int cb   = blockIdx.y;

    const float* b = bb + (size_t)((n * H_ + h) * W_ + w) * 5;
    const float cx = b[0], cy = b[1], bw = b[2], bh = b[3], th = b[4];
    const float st = sinf(th), ct = cosf(th);
    const float vx = bw * ct * 0.5f, vy = bw * st * 0.5f;
    const float wx = -bh * st * 0.5f, wy = bh * ct * 0.5f;
    const float pxs[5] = {cx, cx + vx + wx, cx - vx + wx, cx - vx - wx, cx + vx - wx};
    const float pys[5] = {cy, cy + vy + wy, cy - vy + wy, cy - vy - wy, cy + vy - wy};

    int   off0[5], off1[5];
    float wgt[20];
#pragma unroll
    for (int p = 0; p < 5; ++p) {
        float x = pxs[p] * SCALE;
        float y = pys[p] * SCALE;
        const bool valid = (y >= -1.0f) && (y <= (float)H_) &&
                           (x >= -1.0f) && (x <= (float)W_);
        y = fmaxf(y, 0.0f);
        x = fmaxf(x, 0.0f);
        int yl = min((int)y, H_ - 1);
        int xl = min((int)x, W_ - 1);
        if (yl >= H_ - 1) y = (float)yl;
        if (xl >= W_ - 1) x = (float)xl;
        const int yh = min(yl + 1, H_ - 1);
        const float ly = y - (float)yl, lx = x - (float)xl;
        const float hy = 1.0f - ly,     hx = 1.0f - lx;
        const int xa = min(xl, W_ - 2);
        float wA, wB;
        if (xl < W_ - 1) { wA = hx; wB = lx; }
        else             { wA = 0.0f; wB = 1.0f; }
        const float v = valid ? 1.0f : 0.0f;
        off0[p] = yl * W_ + xa;
        off1[p] = yh * W_ + xa;
        wgt[p * 4 + 0] = v * hy * wA;
        wgt[p * 4 + 1] = v * hy * wB;
        wgt[p * 4 + 2] = v * ly * wA;
        wgt[p * 4 + 3] = v * ly * wB;
    }

    const int hw = h * W_ + w;
    const size_t planeBase = ((size_t)n * C_ + cb * 64 + wave * 16) * HW_;
    const float* fp = feat + planeBase;
    float*       op = out  + planeBase;
    for (int it = 0; it < 16; ++it) {
        float acc = fp[hw];
#pragma unroll
        for (int p = 0; p < 5; ++p) {
            acc += wgt[p * 4 + 0] * fp[off0[p]]
                 + wgt[p * 4 + 1] * fp[off0[p] + 1]
                 + wgt[p * 4 + 2] * fp[off1[p]]
                 + wgt[p * 4 + 3] * fp[off1[p] + 1];
        }
        op[hw] = acc;
        fp += HW_;
        op += HW_;
    }
}

extern "C" void kernel_launch(void* const* d_in, const int* in_sizes, int n_in,
                              void* d_out, int out_size, void* d_ws, size_t ws_size,
                              hipStream_t stream) {
    const float* feat = (const float*)d_in[0];   // [N,C,H,W] fp32
    const float* bbox = (const float*)d_in[1];   // [N,H,W,5] fp32
    float* out = (float*)d_out;

    const size_t nhwcBytes = (size_t)N_ * HW_ * C_ * 2;        // 32 MB bf16
    const size_t geoBytes  = (size_t)N_ * HW_ * 160;           // 10.5 MB
    if (ws_size >= nhwcBytes + geoBytes) {
        uint32* nhwcU = (uint32*)d_ws;
        uint32* geoG  = (uint32*)((char*)d_ws + nhwcBytes);
        nchw2nhwc_geo<<<dim3(HW_ / 256, 2, N_), dim3(1024), 0, stream>>>(feat, bbox, nhwcU, geoG);
        fr_refine<<<dim3(N_ * H_ * (W_ / 32) * 2), dim3(256), 0, stream>>>(nhwcU, geoG, out);
    } else {
        dim3 grid(N_ * H_ * (W_ / 64), C_ / 64, 1);
        fr_kernel<<<grid, dim3(256), 0, stream>>>(feat, bbox, out);
    }
}